// Round 2
// baseline (399.009 us; speedup 1.0000x reference)
//
#include <hip/hip_runtime.h>
#include <hip/hip_bf16.h>

#define NPAIR 4096
#define DIM   768
#define N2    8192
#define BM    128            // rows per block = 4 waves x 32
#define BN    32             // cols per tile
#define NSTRIP 16            // col strips (grid.y)
#define KSTEP 48             // K steps of 16 (DIM/16)
#define GRAN_PER_COL 96      // 16B granules per row (DIM/8)
#define NBI (N2 / BM)        // 64
#define NCJ (N2 / BN)        // 256

constexpr float INV_T = 1.0f / 0.07f;  // also the fixed softmax max M

typedef __bf16 bf16x8 __attribute__((ext_vector_type(8)));
typedef float  f32x16 __attribute__((ext_vector_type(16)));

__device__ inline unsigned short f2bf(float x) {
    return __builtin_bit_cast(unsigned short, (__bf16)x);
}

// ---------------- normalize: one wave per row, fp32 in -> bf16 out ----------
__global__ void knorm(const float* __restrict__ z1, const float* __restrict__ z2,
                      unsigned short* __restrict__ zb) {
    const int row  = blockIdx.x * 4 + (threadIdx.x >> 6);
    const int lane = threadIdx.x & 63;
    const float* src = (row < NPAIR) ? (z1 + (size_t)row * DIM)
                                     : (z2 + (size_t)(row - NPAIR) * DIM);
    float4 v[3];
    float ss = 0.f;
#pragma unroll
    for (int i = 0; i < 3; ++i) {
        v[i] = reinterpret_cast<const float4*>(src)[lane + 64 * i];
        ss += v[i].x * v[i].x + v[i].y * v[i].y + v[i].z * v[i].z + v[i].w * v[i].w;
    }
#pragma unroll
    for (int off = 32; off; off >>= 1) ss += __shfl_xor(ss, off);
    const float scale = 1.0f / fmaxf(sqrtf(ss), 1e-12f);
    ushort4* dst = reinterpret_cast<ushort4*>(zb + (size_t)row * DIM);
#pragma unroll
    for (int i = 0; i < 3; ++i) {
        ushort4 o;
        o.x = f2bf(v[i].x * scale); o.y = f2bf(v[i].y * scale);
        o.z = f2bf(v[i].z * scale); o.w = f2bf(v[i].w * scale);
        dst[lane + 64 * i] = o;
    }
}

// ---------------- positive-pair dots: one wave per pair ---------------------
__global__ void kpos(const unsigned short* __restrict__ zb, float* __restrict__ pos) {
    const int pair = blockIdx.x * 4 + (threadIdx.x >> 6);
    const int lane = threadIdx.x & 63;
    const bf16x8* a = reinterpret_cast<const bf16x8*>(zb + (size_t)pair * DIM);
    const bf16x8* b = reinterpret_cast<const bf16x8*>(zb + (size_t)(pair + NPAIR) * DIM);
    float s = 0.f;
#pragma unroll
    for (int c = 0; c < 2; ++c) {
        const int idx = lane + 64 * c;
        if (idx < GRAN_PER_COL) {
            bf16x8 va = a[idx], vb = b[idx];
#pragma unroll
            for (int j = 0; j < 8; ++j) s += (float)va[j] * (float)vb[j];
        }
    }
#pragma unroll
    for (int off = 32; off; off >>= 1) s += __shfl_xor(s, off);
    if (lane == 0) pos[pair] = s * INV_T;
}

// ---------------- main: triangular row-sums of exp(sim - M) -----------------
// Upper-triangle tiles only; each exp value credited to rowsum[row] (regs)
// and rowsum[col] (LDS strip accumulator, flushed once per block).
// Wave = 32 rows x 32 cols via mfma_f32_32x32x16_bf16; Q entirely in regs.
__global__ __launch_bounds__(256, 2) void klse(const unsigned short* __restrict__ zb,
                                               float* __restrict__ rowsum) {
    __shared__ __align__(16) unsigned short Bs[BN * DIM];   // 48 KB
    __shared__ float csum[NSTRIP * BN];                      // 2 KB
    const int wave = threadIdx.x >> 6;
    const int lane = threadIdx.x & 63;
    const int bi = blockIdx.x;
    const int s  = blockIdx.y;
    const int cj0 = 4 * bi + s;          // first col-tile (>= diagonal start)
    if (cj0 >= NCJ) return;              // block-uniform early out

    for (int i = threadIdx.x; i < NSTRIP * BN; i += 256) csum[i] = 0.f;

    const int rowbase = bi * BM + wave * 32;
    const int hi   = lane >> 5;          // k-octet half
    const int rlo  = lane & 31;          // A row / B col within tile
    // Q fragments: 32 rows x K=768 for this wave (192 VGPRs)
    bf16x8 qf[KSTEP];
    {
        const unsigned short* qp = zb + (size_t)(rowbase + rlo) * DIM + hi * 8;
#pragma unroll
        for (int t = 0; t < KSTEP; ++t)
            qf[t] = *reinterpret_cast<const bf16x8*>(qp + t * 16);
    }

    float psum[16];
#pragma unroll
    for (int r = 0; r < 16; ++r) psum[r] = 0.f;

    int slot = 0;
    for (int cj = cj0; cj < NCJ; cj += NSTRIP, ++slot) {
        const int c0 = cj * BN;
        __syncthreads();  // all waves done reading Bs before overwrite
        // stage BN x DIM bf16; LDS linear, global source pre-XOR-swizzled
#pragma unroll
        for (int i = 0; i < 12; ++i) {
            const int chunk = wave * 12 + i;
            const int g   = chunk * 64 + lane;
            const int col = g / GRAN_PER_COL;
            const int ko  = g - col * GRAN_PER_COL;
            const unsigned short* gsrc =
                zb + (size_t)(c0 + col) * DIM + ((ko ^ (col & 7)) << 3);
            __builtin_amdgcn_global_load_lds(
                (const __attribute__((address_space(1))) unsigned int*)gsrc,
                (__attribute__((address_space(3))) unsigned int*)(Bs + chunk * 512),
                16, 0, 0);
        }
        __syncthreads();

        f32x16 acc = {0.f,0.f,0.f,0.f,0.f,0.f,0.f,0.f,
                      0.f,0.f,0.f,0.f,0.f,0.f,0.f,0.f};
#pragma unroll
        for (int t = 0; t < KSTEP; ++t) {
            const int kk = 2 * t + hi;
            bf16x8 b = *reinterpret_cast<const bf16x8*>(
                &Bs[rlo * DIM + ((kk ^ (rlo & 7)) << 3)]);
            acc = __builtin_amdgcn_mfma_f32_32x32x16_bf16(qf[t], b, acc, 0, 0, 0);
        }

        const int colg = c0 + rlo;
        float cs = 0.f;
        if (cj >= 4 * bi + 4) {          // strictly above diagonal block-row
#pragma unroll
            for (int r = 0; r < 16; ++r) {
                float e = __expf((acc[r] - 1.0f) * INV_T);
                psum[r] += e;
                cs += e;
            }
        } else {                          // diagonal region: keep col > row only
#pragma unroll
            for (int r = 0; r < 16; ++r) {
                const int rowg = rowbase + (r & 3) + 8 * (r >> 2) + 4 * hi;
                float e = __expf((acc[r] - 1.0f) * INV_T);
                e = (colg > rowg) ? e : 0.f;
                psum[r] += e;
                cs += e;
            }
        }
        atomicAdd(&csum[slot * BN + rlo], cs);   // lanes l and l+32 share a col
    }

    // row-side: reduce psum across the 32 lanes of each half, then atomics
#pragma unroll
    for (int r = 0; r < 16; ++r) {
#pragma unroll
        for (int m = 1; m < 32; m <<= 1) psum[r] += __shfl_xor(psum[r], m);
    }
    if ((lane & 31) == 0) {
#pragma unroll
        for (int r = 0; r < 16; ++r)
            atomicAdd(&rowsum[rowbase + (r & 3) + 8 * (r >> 2) + 4 * hi], psum[r]);
    }

    // col-side flush
    __syncthreads();
    for (int i = threadIdx.x; i < NSTRIP * BN; i += 256) {
        const int sl = i / BN, c = i - sl * BN;
        const int cj = cj0 + sl * NSTRIP;
        if (cj < NCJ) atomicAdd(&rowsum[cj * BN + c], csum[i]);
    }
}

// ---------------- final: loss = mean(M + log S_i - pos) ---------------------
__global__ void kfinal(const float* __restrict__ rowsum, const float* __restrict__ pos,
                       float* __restrict__ out) {
    __shared__ float red[8];
    const int tid = threadIdx.x;
    float s = 0.f;
    for (int i = tid; i < N2; i += 512) {
        const int p = (i < NPAIR) ? i : i - NPAIR;
        s += INV_T + __logf(rowsum[i]) - pos[p];
    }
#pragma unroll
    for (int off = 32; off; off >>= 1) s += __shfl_xor(s, off);
    if ((tid & 63) == 0) red[tid >> 6] = s;
    __syncthreads();
    if (tid == 0) {
        float t = 0.f;
#pragma unroll
        for (int w = 0; w < 8; ++w) t += red[w];
        out[0] = t / (float)N2;
    }
}

extern "C" void kernel_launch(void* const* d_in, const int* in_sizes, int n_in,
                              void* d_out, int out_size, void* d_ws, size_t ws_size,
                              hipStream_t stream) {
    const float* z1 = (const float*)d_in[0];
    const float* z2 = (const float*)d_in[1];
    unsigned short* zb = (unsigned short*)d_ws;                       // 8192*768 bf16
    float* rowsum = (float*)((char*)d_ws + (size_t)N2 * DIM * 2);     // 8192 f32
    float* pos = rowsum + N2;                                         // 4096 f32
    float* out = (float*)d_out;

    hipLaunchKernelGGL(knorm, dim3(N2 / 4), dim3(256), 0, stream, z1, z2, zb);
    hipLaunchKernelGGL(kpos, dim3(NPAIR / 4), dim3(256), 0, stream, zb, pos);
    hipMemsetAsync(rowsum, 0, N2 * sizeof(float), stream);
    hipLaunchKernelGGL(klse, dim3(NBI, NSTRIP), dim3(256), 0, stream, zb, rowsum);
    hipLaunchKernelGGL(kfinal, dim3(1), dim3(512), 0, stream, rowsum, pos, out);
}

// Round 3
// 321.052 us; speedup vs baseline: 1.2428x; 1.2428x over previous
//
#include <hip/hip_runtime.h>
#include <hip/hip_bf16.h>

#define NPAIR 4096
#define DIM   768
#define N2    8192
#define BM    128            // rows per block = 4 waves x 32
#define BN    32             // cols per tile
#define NSTRIP 8             // col strips (grid.y); 1024 cols each
#define COLS_PER (N2 / NSTRIP)         // 1024
#define KSTEP 48             // K steps of 16 (DIM/16)
#define GRAN_PER_COL 96      // 16B granules per row (DIM/8)
#define NBI (N2 / BM)        // 64

constexpr float INV_T = 1.0f / 0.07f;  // also the fixed softmax max M

typedef __bf16 bf16x8 __attribute__((ext_vector_type(8)));
typedef float  f32x16 __attribute__((ext_vector_type(16)));

__device__ inline unsigned short f2bf(float x) {
    return __builtin_bit_cast(unsigned short, (__bf16)x);
}

// ---------------- normalize: one wave per row, fp32 in -> bf16 out ----------
__global__ void knorm(const float* __restrict__ z1, const float* __restrict__ z2,
                      unsigned short* __restrict__ zb) {
    const int row  = blockIdx.x * 4 + (threadIdx.x >> 6);
    const int lane = threadIdx.x & 63;
    const float* src = (row < NPAIR) ? (z1 + (size_t)row * DIM)
                                     : (z2 + (size_t)(row - NPAIR) * DIM);
    float4 v[3];
    float ss = 0.f;
#pragma unroll
    for (int i = 0; i < 3; ++i) {
        v[i] = reinterpret_cast<const float4*>(src)[lane + 64 * i];
        ss += v[i].x * v[i].x + v[i].y * v[i].y + v[i].z * v[i].z + v[i].w * v[i].w;
    }
#pragma unroll
    for (int off = 32; off; off >>= 1) ss += __shfl_xor(ss, off);
    const float scale = 1.0f / fmaxf(sqrtf(ss), 1e-12f);
    ushort4* dst = reinterpret_cast<ushort4*>(zb + (size_t)row * DIM);
#pragma unroll
    for (int i = 0; i < 3; ++i) {
        ushort4 o;
        o.x = f2bf(v[i].x * scale); o.y = f2bf(v[i].y * scale);
        o.z = f2bf(v[i].z * scale); o.w = f2bf(v[i].w * scale);
        dst[lane + 64 * i] = o;
    }
}

// ---------------- positive-pair dots: one wave per pair ---------------------
__global__ void kpos(const unsigned short* __restrict__ zb, float* __restrict__ pos) {
    const int pair = blockIdx.x * 4 + (threadIdx.x >> 6);
    const int lane = threadIdx.x & 63;
    const bf16x8* a = reinterpret_cast<const bf16x8*>(zb + (size_t)pair * DIM);
    const bf16x8* b = reinterpret_cast<const bf16x8*>(zb + (size_t)(pair + NPAIR) * DIM);
    float s = 0.f;
#pragma unroll
    for (int c = 0; c < 2; ++c) {
        const int idx = lane + 64 * c;
        if (idx < GRAN_PER_COL) {
            bf16x8 va = a[idx], vb = b[idx];
#pragma unroll
            for (int j = 0; j < 8; ++j) s += (float)va[j] * (float)vb[j];
        }
    }
#pragma unroll
    for (int off = 32; off; off >>= 1) s += __shfl_xor(s, off);
    if (lane == 0) pos[pair] = s * INV_T;
}

// ---------------- main: row-sums of exp(sim - M), diag masked ---------------
// Full N^2 sweep (R0's L2-aligned pattern). Wave = 32 rows x 32 cols via
// mfma_f32_32x32x16_bf16; Q entirely in registers (192 VGPRs).
// amdgpu_waves_per_eu(2,2): allocator targets 2 waves/SIMD (<=256 regs).
__global__ __launch_bounds__(256)
__attribute__((amdgpu_waves_per_eu(2, 2)))
void klse(const unsigned short* __restrict__ zb, float* __restrict__ rowsum) {
    __shared__ __align__(16) unsigned short Bs[BN * DIM];   // 48 KB
    const int wave = threadIdx.x >> 6;
    const int lane = threadIdx.x & 63;
    const int bi = blockIdx.x;
    const int s  = blockIdx.y;

    const int rowblk  = bi * BM;
    const int rowbase = rowblk + wave * 32;
    const int hi  = lane >> 5;           // k-octet half
    const int rlo = lane & 31;           // A row / B col within tile

    // Q fragments: 32 rows x K=768 for this wave (192 VGPRs)
    bf16x8 qf[KSTEP];
    {
        const unsigned short* qp = zb + (size_t)(rowbase + rlo) * DIM + hi * 8;
#pragma unroll
        for (int t = 0; t < KSTEP; ++t)
            qf[t] = *reinterpret_cast<const bf16x8*>(qp + t * 16);
    }

    float psum[16];
#pragma unroll
    for (int r = 0; r < 16; ++r) psum[r] = 0.f;

    for (int ct = 0; ct < COLS_PER / BN; ++ct) {
        const int c0 = s * COLS_PER + ct * BN;
        __syncthreads();  // all waves done reading Bs before overwrite
        // stage BN x DIM bf16; LDS linear, global source pre-XOR-swizzled
#pragma unroll
        for (int i = 0; i < 12; ++i) {
            const int chunk = wave * 12 + i;
            const int g   = chunk * 64 + lane;
            const int col = g / GRAN_PER_COL;
            const int ko  = g - col * GRAN_PER_COL;
            const unsigned short* gsrc =
                zb + (size_t)(c0 + col) * DIM + ((ko ^ (col & 7)) << 3);
            __builtin_amdgcn_global_load_lds(
                (const __attribute__((address_space(1))) unsigned int*)gsrc,
                (__attribute__((address_space(3))) unsigned int*)(Bs + chunk * 512),
                16, 0, 0);
        }
        __syncthreads();

        f32x16 acc = {0.f,0.f,0.f,0.f,0.f,0.f,0.f,0.f,
                      0.f,0.f,0.f,0.f,0.f,0.f,0.f,0.f};
#pragma unroll
        for (int t = 0; t < KSTEP; ++t) {
            const int kk = 2 * t + hi;
            bf16x8 b = *reinterpret_cast<const bf16x8*>(
                &Bs[rlo * DIM + ((kk ^ (rlo & 7)) << 3)]);
            acc = __builtin_amdgcn_mfma_f32_32x32x16_bf16(qf[t], b, acc, 0, 0, 0);
        }

        const bool on_diag = (c0 + BN > rowblk) && (c0 < rowblk + BM);
        if (!on_diag) {
#pragma unroll
            for (int r = 0; r < 16; ++r)
                psum[r] += __expf((acc[r] - 1.0f) * INV_T);
        } else {
            const int colg = c0 + rlo;
#pragma unroll
            for (int r = 0; r < 16; ++r) {
                const int rowg = rowbase + (r & 3) + 8 * (r >> 2) + 4 * hi;
                float e = __expf((acc[r] - 1.0f) * INV_T);
                psum[r] += (rowg == colg) ? 0.f : e;
            }
        }
    }

    // reduce psum across the 32 col-lanes of each half, then atomics
#pragma unroll
    for (int r = 0; r < 16; ++r) {
#pragma unroll
        for (int m = 1; m < 32; m <<= 1) psum[r] += __shfl_xor(psum[r], m);
    }
    if ((lane & 31) == 0) {
#pragma unroll
        for (int r = 0; r < 16; ++r)
            atomicAdd(&rowsum[rowbase + (r & 3) + 8 * (r >> 2) + 4 * hi], psum[r]);
    }
}

// ---------------- final: loss = mean(M + log S_i - pos) ---------------------
__global__ void kfinal(const float* __restrict__ rowsum, const float* __restrict__ pos,
                       float* __restrict__ out) {
    __shared__ float red[8];
    const int tid = threadIdx.x;
    float s = 0.f;
    for (int i = tid; i < N2; i += 512) {
        const int p = (i < NPAIR) ? i : i - NPAIR;
        s += INV_T + __logf(rowsum[i]) - pos[p];
    }
#pragma unroll
    for (int off = 32; off; off >>= 1) s += __shfl_xor(s, off);
    if ((tid & 63) == 0) red[tid >> 6] = s;
    __syncthreads();
    if (tid == 0) {
        float t = 0.f;
#pragma unroll
        for (int w = 0; w < 8; ++w) t += red[w];
        out[0] = t / (float)N2;
    }
}

extern "C" void kernel_launch(void* const* d_in, const int* in_sizes, int n_in,
                              void* d_out, int out_size, void* d_ws, size_t ws_size,
                              hipStream_t stream) {
    const float* z1 = (const float*)d_in[0];
    const float* z2 = (const float*)d_in[1];
    unsigned short* zb = (unsigned short*)d_ws;                       // 8192*768 bf16
    float* rowsum = (float*)((char*)d_ws + (size_t)N2 * DIM * 2);     // 8192 f32
    float* pos = rowsum + N2;                                         // 4096 f32
    float* out = (float*)d_out;

    hipLaunchKernelGGL(knorm, dim3(N2 / 4), dim3(256), 0, stream, z1, z2, zb);
    hipLaunchKernelGGL(kpos, dim3(NPAIR / 4), dim3(256), 0, stream, zb, pos);
    hipMemsetAsync(rowsum, 0, N2 * sizeof(float), stream);
    hipLaunchKernelGGL(klse, dim3(NBI, NSTRIP), dim3(256), 0, stream, zb, rowsum);
    hipLaunchKernelGGL(kfinal, dim3(1), dim3(512), 0, stream, rowsum, pos, out);
}

// Round 4
// 168.943 us; speedup vs baseline: 2.3618x; 1.9004x over previous
//
#include <hip/hip_runtime.h>
#include <hip/hip_bf16.h>

#define NPAIR 4096
#define DIM   768
#define N2    8192
#define BM    128            // block rows (4 waves as 2x2, each 64x64)
#define BNB   128            // block cols per col-block
#define KBLK  64             // K tile (8 octets of 8 bf16)
#define KITER (DIM / KBLK)   // 12
#define NSTRIP 16            // grid.y
#define CPB   ((N2 / BNB) / NSTRIP)    // 4 col-blocks per strip
#define NBI   (N2 / BM)      // 64

constexpr float INV_T = 1.0f / 0.07f;  // also the fixed softmax max M

typedef __bf16 bf16x8 __attribute__((ext_vector_type(8)));
typedef float  f32x16 __attribute__((ext_vector_type(16)));

__device__ inline unsigned short f2bf(float x) {
    return __builtin_bit_cast(unsigned short, (__bf16)x);
}

// ---------------- normalize: one wave per row, fp32 in -> bf16 out ----------
__global__ void knorm(const float* __restrict__ z1, const float* __restrict__ z2,
                      unsigned short* __restrict__ zb) {
    const int row  = blockIdx.x * 4 + (threadIdx.x >> 6);
    const int lane = threadIdx.x & 63;
    const float* src = (row < NPAIR) ? (z1 + (size_t)row * DIM)
                                     : (z2 + (size_t)(row - NPAIR) * DIM);
    float4 v[3];
    float ss = 0.f;
#pragma unroll
    for (int i = 0; i < 3; ++i) {
        v[i] = reinterpret_cast<const float4*>(src)[lane + 64 * i];
        ss += v[i].x * v[i].x + v[i].y * v[i].y + v[i].z * v[i].z + v[i].w * v[i].w;
    }
#pragma unroll
    for (int off = 32; off; off >>= 1) ss += __shfl_xor(ss, off);
    const float scale = 1.0f / fmaxf(sqrtf(ss), 1e-12f);
    ushort4* dst = reinterpret_cast<ushort4*>(zb + (size_t)row * DIM);
#pragma unroll
    for (int i = 0; i < 3; ++i) {
        ushort4 o;
        o.x = f2bf(v[i].x * scale); o.y = f2bf(v[i].y * scale);
        o.z = f2bf(v[i].z * scale); o.w = f2bf(v[i].w * scale);
        dst[lane + 64 * i] = o;
    }
}

// ---------------- positive-pair dots: one wave per pair ---------------------
__global__ void kpos(const unsigned short* __restrict__ zb, float* __restrict__ pos) {
    const int pair = blockIdx.x * 4 + (threadIdx.x >> 6);
    const int lane = threadIdx.x & 63;
    const bf16x8* a = reinterpret_cast<const bf16x8*>(zb + (size_t)pair * DIM);
    const bf16x8* b = reinterpret_cast<const bf16x8*>(zb + (size_t)(pair + NPAIR) * DIM);
    float s = 0.f;
#pragma unroll
    for (int c = 0; c < 2; ++c) {
        const int idx = lane + 64 * c;
        if (idx < 96) {
            bf16x8 va = a[idx], vb = b[idx];
#pragma unroll
            for (int j = 0; j < 8; ++j) s += (float)va[j] * (float)vb[j];
        }
    }
#pragma unroll
    for (int off = 32; off; off >>= 1) s += __shfl_xor(s, off);
    if (lane == 0) pos[pair] = s * INV_T;
}

// ---------------- main: row-sums of exp(sim - M), diag masked ---------------
// Classic register-blocked GEMM: block 128x128, wave 64x64 (2x2 sub-tiles of
// mfma_f32_32x32x16_bf16), A and B staged in LDS (16KB each) per K-tile via
// global_load_lds with XOR-swizzled source; fits 128 VGPRs (no Q-in-regs).
__global__ __launch_bounds__(256) void klse(const unsigned short* __restrict__ zb,
                                            float* __restrict__ rowsum) {
    __shared__ __align__(16) unsigned short As[BM * KBLK];   // 16 KB
    __shared__ __align__(16) unsigned short Bs[BNB * KBLK];  // 16 KB
    const int tid  = threadIdx.x;
    const int wave = tid >> 6;
    const int lane = tid & 63;
    const int wr = wave >> 1, wc = wave & 1;
    const int hi = lane >> 5, rlo = lane & 31;
    const int bi = blockIdx.x;
    const int rb = bi * BM;
    const int sw = rlo & 7;                       // row/col swizzle bits

    // LDS element offsets (bf16 units) for fragment rows/cols
    const int raA = (wr * 64 + rlo) * KBLK;       // A sub 0 row base
    const int raB = raA + 32 * KBLK;              // A sub 1
    const int caA = (wc * 64 + rlo) * KBLK;       // B sub 0 col base
    const int caB = caA + 32 * KBLK;              // B sub 1

    for (int ct = 0; ct < CPB; ++ct) {
        const int cblk = blockIdx.y * CPB + ct;
        const int c0 = cblk * BNB;

        f32x16 acc00 = {}, acc01 = {}, acc10 = {}, acc11 = {};

        for (int kt = 0; kt < KITER; ++kt) {
            const int kbase = kt * KBLK;
            __syncthreads();   // previous tile reads complete before overwrite
#pragma unroll
            for (int i = 0; i < 4; ++i) {
                const int g = i * 256 + tid;       // granule index (16B)
                const int r = g >> 3, slot = g & 7;
                const int ksrc = kbase + ((slot ^ (r & 7)) << 3);
                const unsigned short* srcA = zb + (size_t)(rb + r) * DIM + ksrc;
                const unsigned short* srcB = zb + (size_t)(c0 + r) * DIM + ksrc;
                __builtin_amdgcn_global_load_lds(
                    (const __attribute__((address_space(1))) unsigned int*)srcA,
                    (__attribute__((address_space(3))) unsigned int*)(As + g * 8),
                    16, 0, 0);
                __builtin_amdgcn_global_load_lds(
                    (const __attribute__((address_space(1))) unsigned int*)srcB,
                    (__attribute__((address_space(3))) unsigned int*)(Bs + g * 8),
                    16, 0, 0);
            }
            __syncthreads();

#pragma unroll
            for (int t = 0; t < 4; ++t) {
                const int ko = t * 2 + hi;
                const int so = (ko ^ sw) << 3;     // swizzled octet offset
                bf16x8 a0 = *reinterpret_cast<const bf16x8*>(&As[raA + so]);
                bf16x8 a1 = *reinterpret_cast<const bf16x8*>(&As[raB + so]);
                bf16x8 b0 = *reinterpret_cast<const bf16x8*>(&Bs[caA + so]);
                bf16x8 b1 = *reinterpret_cast<const bf16x8*>(&Bs[caB + so]);
                acc00 = __builtin_amdgcn_mfma_f32_32x32x16_bf16(a0, b0, acc00, 0, 0, 0);
                acc01 = __builtin_amdgcn_mfma_f32_32x32x16_bf16(a0, b1, acc01, 0, 0, 0);
                acc10 = __builtin_amdgcn_mfma_f32_32x32x16_bf16(a1, b0, acc10, 0, 0, 0);
                acc11 = __builtin_amdgcn_mfma_f32_32x32x16_bf16(a1, b1, acc11, 0, 0, 0);
            }
        }

        // epilogue: exp, diagonal mask, row-sum reduce, atomic flush
        const bool on_diag = (cblk == bi);
        const int row0b = rb + wr * 64 + 4 * hi;
        const int col0  = c0 + wc * 64 + rlo;
        float ps0[16], ps1[16];
#pragma unroll
        for (int r = 0; r < 16; ++r) {
            const int rg0 = row0b + (r & 3) + 8 * (r >> 2);
            float e00 = __expf((acc00[r] - 1.0f) * INV_T);
            float e01 = __expf((acc01[r] - 1.0f) * INV_T);
            float e10 = __expf((acc10[r] - 1.0f) * INV_T);
            float e11 = __expf((acc11[r] - 1.0f) * INV_T);
            if (on_diag) {
                if (rg0 == col0)           e00 = 0.f;
                if (rg0 == col0 + 32)      e01 = 0.f;
                if (rg0 + 32 == col0)      e10 = 0.f;
                if (rg0 + 32 == col0 + 32) e11 = 0.f;
            }
            ps0[r] = e00 + e01;
            ps1[r] = e10 + e11;
        }
#pragma unroll
        for (int r = 0; r < 16; ++r) {
#pragma unroll
            for (int m = 1; m < 32; m <<= 1) {
                ps0[r] += __shfl_xor(ps0[r], m);
                ps1[r] += __shfl_xor(ps1[r], m);
            }
        }
        if (rlo == 0) {
#pragma unroll
            for (int r = 0; r < 16; ++r) {
                const int rg0 = row0b + (r & 3) + 8 * (r >> 2);
                atomicAdd(&rowsum[rg0], ps0[r]);
                atomicAdd(&rowsum[rg0 + 32], ps1[r]);
            }
        }
        __syncthreads();   // accs/epilogue done before next ct re-stages
    }
}

// ---------------- final: loss = mean(M + log S_i - pos) ---------------------
__global__ void kfinal(const float* __restrict__ rowsum, const float* __restrict__ pos,
                       float* __restrict__ out) {
    __shared__ float red[8];
    const int tid = threadIdx.x;
    float s = 0.f;
    for (int i = tid; i < N2; i += 512) {
        const int p = (i < NPAIR) ? i : i - NPAIR;
        s += INV_T + __logf(rowsum[i]) - pos[p];
    }
#pragma unroll
    for (int off = 32; off; off >>= 1) s += __shfl_xor(s, off);
    if ((tid & 63) == 0) red[tid >> 6] = s;
    __syncthreads();
    if (tid == 0) {
        float t = 0.f;
#pragma unroll
        for (int w = 0; w < 8; ++w) t += red[w];
        out[0] = t / (float)N2;
    }
}

extern "C" void kernel_launch(void* const* d_in, const int* in_sizes, int n_in,
                              void* d_out, int out_size, void* d_ws, size_t ws_size,
                              hipStream_t stream) {
    const float* z1 = (const float*)d_in[0];
    const float* z2 = (const float*)d_in[1];
    unsigned short* zb = (unsigned short*)d_ws;                       // 8192*768 bf16
    float* rowsum = (float*)((char*)d_ws + (size_t)N2 * DIM * 2);     // 8192 f32
    float* pos = rowsum + N2;                                         // 4096 f32
    float* out = (float*)d_out;

    hipLaunchKernelGGL(knorm, dim3(N2 / 4), dim3(256), 0, stream, z1, z2, zb);
    hipLaunchKernelGGL(kpos, dim3(NPAIR / 4), dim3(256), 0, stream, zb, pos);
    hipMemsetAsync(rowsum, 0, N2 * sizeof(float), stream);
    hipLaunchKernelGGL(klse, dim3(NBI, NSTRIP), dim3(256), 0, stream, zb, rowsum);
    hipLaunchKernelGGL(kfinal, dim3(1), dim3(512), 0, stream, rowsum, pos, out);
}